// Round 1
// baseline (488.847 us; speedup 1.0000x reference)
//
#include <hip/hip_runtime.h>
#include <math.h>

// Problem constants (fixed by the harness/reference):
// B=2, S=8192, H=16, D=128, W=4 (window = W+1 = 5 taps)
constexpr int B = 2;
constexpr int S = 8192;
constexpr int H = 16;
constexpr int D = 128;
constexpr int W = 4;
constexpr float SCALE = 0.08838834764831845f;  // 1/sqrt(128)

// One 32-lane group per (b,s,h) output row. Each lane holds 4 contiguous
// d-elements (float4, 16B/lane). Block = 256 threads = 8 groups; head index
// is fastest over groups so a block's q-reads span one contiguous 4KB chunk.
__global__ __launch_bounds__(256) void gdr_kernel(
    const float* __restrict__ q, const float* __restrict__ k,
    const float* __restrict__ v, const float* __restrict__ a,
    const float* __restrict__ b, float* __restrict__ out)
{
    const int tid   = threadIdx.x;
    const int group = tid >> 5;   // 0..7
    const int lane  = tid & 31;

    const long long gid = (long long)blockIdx.x * 8 + group;  // (b,s,h) flat, h fastest
    const int h  = (int)(gid & (H - 1));
    const long long bs = gid >> 4;           // b*S + s
    const int s  = (int)(bs & (S - 1));

    const long long rowBase = bs * (long long)(H * D) + (long long)h * D;
    const int d0 = lane * 4;

    if (s == 0) {
        // position 0 is special-cased: out = v_0
        const float4 v4 = *(const float4*)(v + rowBase + d0);
        *(float4*)(out + rowBase + d0) = v4;
        return;
    }

    const float4 q4 = *(const float4*)(q + rowBase + d0);
    const float ai  = a[bs * H + h];
    float4 acc = make_float4(0.f, 0.f, 0.f, 0.f);

#pragma unroll
    for (int delta = 0; delta <= W; ++delta) {
        const int j = s - delta;
        if (j < 0) continue;  // zero-padded positions contribute nothing
        const long long jBase = rowBase - (long long)delta * (H * D);
        const float4 k4 = *(const float4*)(k + jBase + d0);
        const float4 v4 = *(const float4*)(v + jBase + d0);

        float p = q4.x * k4.x + q4.y * k4.y + q4.z * k4.z + q4.w * k4.w;
        // reduce across the 32-lane group
        p += __shfl_xor(p, 16, 64);
        p += __shfl_xor(p, 8, 64);
        p += __shfl_xor(p, 4, 64);
        p += __shfl_xor(p, 2, 64);
        p += __shfl_xor(p, 1, 64);

        const float bj = b[(bs - (long long)delta) * H + h];
        const float g  = 1.0f / (1.0f + __expf(-(ai * bj)));
        const float wg = p * SCALE * g;
        acc.x += wg * v4.x;
        acc.y += wg * v4.y;
        acc.z += wg * v4.z;
        acc.w += wg * v4.w;
    }

    *(float4*)(out + rowBase + d0) = acc;
}

extern "C" void kernel_launch(void* const* d_in, const int* in_sizes, int n_in,
                              void* d_out, int out_size, void* d_ws, size_t ws_size,
                              hipStream_t stream) {
    const float* q = (const float*)d_in[0];
    const float* k = (const float*)d_in[1];
    const float* v = (const float*)d_in[2];
    const float* a = (const float*)d_in[3];
    const float* b = (const float*)d_in[4];
    float* out = (float*)d_out;

    // B*S*H rows, 8 rows per block
    const int nRows = B * S * H;           // 262144
    const int blocks = nRows / 8;          // 32768
    gdr_kernel<<<blocks, 256, 0, stream>>>(q, k, v, a, b, out);
}

// Round 2
// 412.040 us; speedup vs baseline: 1.1864x; 1.1864x over previous
//
#include <hip/hip_runtime.h>
#include <math.h>

// Problem constants (fixed by the harness/reference):
// B=2, S=8192, H=16, D=128, W=4 (window = W+1 = 5 taps)
constexpr int B = 2;
constexpr int S = 8192;
constexpr int H = 16;
constexpr int D = 128;
constexpr int W = 4;
constexpr float SCALE = 0.08838834764831845f;  // 1/sqrt(128)

// One 32-lane group per (b,s,h) output row; each lane owns a float4 of d.
// Work mapping (round 2): a block's 8 groups take 8 CONSECUTIVE s positions
// for the SAME (b,h) -> the 5-tap k/v window overlap (12KB working set) is
// reused inside one CU's L1 instead of being re-fetched from HBM by blocks
// on different XCDs (round-1 FETCH was 728MB vs 410MB unique).
// XCD swizzle: blockIdx%8 = XCD (round-robin dispatch heuristic); S is split
// into 8 contiguous 1024-position segments, one per XCD, so halo reuse across
// adjacent s-chunks stays within a single XCD's L2.
__global__ __launch_bounds__(256) void gdr_kernel(
    const float* __restrict__ q, const float* __restrict__ k,
    const float* __restrict__ v, const float* __restrict__ a,
    const float* __restrict__ b, float* __restrict__ out)
{
    const int tid   = threadIdx.x;
    const int group = tid >> 5;   // 0..7
    const int lane  = tid & 31;

    const int bid = blockIdx.x;
    const int xcd = bid & 7;          // target XCD (round-robin heuristic)
    const int j   = bid >> 3;         // 0..4095: per-XCD work index
    const int c   = j & 127;          // s-chunk within this XCD's segment
    const int bh  = j >> 7;           // 0..31
    const int h   = bh & (H - 1);
    const int bb  = bh >> 4;          // batch

    const int s = xcd * (S / 8) + c * 8 + group;   // consecutive s per group
    const long long bs = (long long)bb * S + s;

    const long long rowBase = bs * (long long)(H * D) + (long long)h * D;
    const int d0 = lane * 4;

    if (s == 0) {
        // position 0 is special-cased: out = v_0
        const float4 v4 = *(const float4*)(v + rowBase + d0);
        *(float4*)(out + rowBase + d0) = v4;
        return;
    }

    const float4 q4 = *(const float4*)(q + rowBase + d0);
    const float ai  = a[bs * H + h];
    float4 acc = make_float4(0.f, 0.f, 0.f, 0.f);

#pragma unroll
    for (int delta = 0; delta <= W; ++delta) {
        const int jj = s - delta;
        if (jj < 0) continue;  // zero-padded positions contribute nothing
        const long long jBase = rowBase - (long long)delta * (H * D);
        const float4 k4 = *(const float4*)(k + jBase + d0);
        const float4 v4 = *(const float4*)(v + jBase + d0);

        float p = q4.x * k4.x + q4.y * k4.y + q4.z * k4.z + q4.w * k4.w;
        // reduce across the 32-lane group
        p += __shfl_xor(p, 16, 64);
        p += __shfl_xor(p, 8, 64);
        p += __shfl_xor(p, 4, 64);
        p += __shfl_xor(p, 2, 64);
        p += __shfl_xor(p, 1, 64);

        const float bj = b[(bs - (long long)delta) * H + h];
        const float g  = 1.0f / (1.0f + __expf(-(ai * bj)));
        const float wg = p * SCALE * g;
        acc.x += wg * v4.x;
        acc.y += wg * v4.y;
        acc.z += wg * v4.z;
        acc.w += wg * v4.w;
    }

    *(float4*)(out + rowBase + d0) = acc;
}

extern "C" void kernel_launch(void* const* d_in, const int* in_sizes, int n_in,
                              void* d_out, int out_size, void* d_ws, size_t ws_size,
                              hipStream_t stream) {
    const float* q = (const float*)d_in[0];
    const float* k = (const float*)d_in[1];
    const float* v = (const float*)d_in[2];
    const float* a = (const float*)d_in[3];
    const float* b = (const float*)d_in[4];
    float* out = (float*)d_out;

    // B*S*H rows, 8 rows per block (8 consecutive s, one head)
    const int nRows = B * S * H;           // 262144
    const int blocks = nRows / 8;          // 32768
    gdr_kernel<<<blocks, 256, 0, stream>>>(q, k, v, a, b, out);
}

// Round 3
// 401.905 us; speedup vs baseline: 1.2163x; 1.0252x over previous
//
#include <hip/hip_runtime.h>
#include <math.h>

// Problem constants (fixed by the harness/reference):
// B=2, S=8192, H=16, D=128, W=4 (window = W+1 = 5 taps)
constexpr int B = 2;
constexpr int S = 8192;
constexpr int H = 16;
constexpr int D = 128;
constexpr int W = 4;
constexpr float SCALE = 0.08838834764831845f;  // 1/sqrt(128)

// DPP butterfly add: x += lanepermute(x). CTRL: 0xB1=quad_perm(1,0,3,2)=xor1,
// 0x4E=quad_perm(2,3,0,1)=xor2, 0x141=row_half_mirror(i^7, crosses 4-groups),
// 0x140=row_mirror(i^15, crosses 8-halves). All VALU-pipe, no DS.
template <int CTRL>
__device__ __forceinline__ float dpp_xadd(float x) {
    int r = __builtin_amdgcn_update_dpp(0, __float_as_int(x), CTRL, 0xF, 0xF, false);
    return x + __int_as_float(r);
}

// Reduce across the 32-lane group: 4 DPP steps (VALU) + one ds_swizzle xor16.
__device__ __forceinline__ float group_reduce32(float p) {
    p = dpp_xadd<0xB1>(p);    // xor 1
    p = dpp_xadd<0x4E>(p);    // xor 2
    p = dpp_xadd<0x141>(p);   // xor 4 (half-mirror)
    p = dpp_xadd<0x140>(p);   // xor 8 (mirror)
    int t = __builtin_amdgcn_ds_swizzle(__float_as_int(p), 0x401F);  // xor 16
    return p + __int_as_float(t);
}

// One 32-lane group per (b,s,h) output row; each lane owns a float4 of d.
// A block's 8 groups take 8 CONSECUTIVE s for the SAME (b,h) (L1 reuse of the
// 5-tap k/v window); blockIdx%8 = XCD, S split into 8 contiguous segments so
// halo reuse stays within one XCD's L2 (round 2: FETCH 728->200MB).
__global__ __launch_bounds__(256) void gdr_kernel(
    const float* __restrict__ q, const float* __restrict__ k,
    const float* __restrict__ v, const float* __restrict__ a,
    const float* __restrict__ b, float* __restrict__ out)
{
    const int tid   = threadIdx.x;
    const int group = tid >> 5;   // 0..7
    const int lane  = tid & 31;

    const int bid = blockIdx.x;
    const int xcd = bid & 7;          // target XCD (round-robin heuristic)
    const int j   = bid >> 3;         // 0..4095: per-XCD work index
    const int c   = j & 127;          // s-chunk within this XCD's segment
    const int bh  = j >> 7;           // 0..31
    const int h   = bh & (H - 1);
    const int bb  = bh >> 4;          // batch

    const int s = xcd * (S / 8) + c * 8 + group;   // consecutive s per group
    const long long bs = (long long)bb * S + s;

    const long long rowBase = bs * (long long)(H * D) + (long long)h * D;
    const int d0 = lane * 4;

    if (s == 0) {
        // position 0 is special-cased: out = v_0
        const float4 v4 = *(const float4*)(v + rowBase + d0);
        *(float4*)(out + rowBase + d0) = v4;
        return;
    }

    const float4 q4 = *(const float4*)(q + rowBase + d0);
    const float ai  = a[bs * H + h];
    float4 acc = make_float4(0.f, 0.f, 0.f, 0.f);

#pragma unroll
    for (int delta = 0; delta <= W; ++delta) {
        const int jj = s - delta;
        if (jj < 0) continue;  // zero-padded positions contribute nothing
        const long long jBase = rowBase - (long long)delta * (H * D);
        const float4 k4 = *(const float4*)(k + jBase + d0);
        const float4 v4 = *(const float4*)(v + jBase + d0);

        float p = q4.x * k4.x + q4.y * k4.y + q4.z * k4.z + q4.w * k4.w;
        p = group_reduce32(p);   // DPP butterfly + 1 swizzle (was 5 bpermutes)

        const float bj = b[(bs - (long long)delta) * H + h];
        const float g  = 1.0f / (1.0f + __expf(-(ai * bj)));
        const float wg = p * SCALE * g;
        acc.x += wg * v4.x;
        acc.y += wg * v4.y;
        acc.z += wg * v4.z;
        acc.w += wg * v4.w;
    }

    *(float4*)(out + rowBase + d0) = acc;
}

extern "C" void kernel_launch(void* const* d_in, const int* in_sizes, int n_in,
                              void* d_out, int out_size, void* d_ws, size_t ws_size,
                              hipStream_t stream) {
    const float* q = (const float*)d_in[0];
    const float* k = (const float*)d_in[1];
    const float* v = (const float*)d_in[2];
    const float* a = (const float*)d_in[3];
    const float* b = (const float*)d_in[4];
    float* out = (float*)d_out;

    // B*S*H rows, 8 rows per block (8 consecutive s, one head)
    const int nRows = B * S * H;           // 262144
    const int blocks = nRows / 8;          // 32768
    gdr_kernel<<<blocks, 256, 0, stream>>>(q, k, v, a, b, out);
}